// Round 8
// baseline (704.345 us; speedup 1.0000x reference)
//
#include <hip/hip_runtime.h>
#include <hip/hip_bf16.h>

// NeuralODE RK4, bf16 MFMA persistent kernel, swapped-operand layout.
// BS=1024, ZDIM=HID=256, TLEN=128 -> 127 steps x 4 stages = 508 f-evals.
//
// Measured model: LDS cost is per-wave DELIVERY (1KB per b128 wave-read,
// broadcast or not — R7 falsified the distinct-address theory). Reads/CU =
// waves x 16/stage. 8 waves = 128KB/stage (~1540cy floor, R5 503us). This
// revision: 4 waves x 64 cols (256 thr, 1 wave/SIMD) -> 64KB/stage, WITH the
// two R6 failure modes fixed:
//  (a) all 8 b128 reads issued as an up-front named batch per GEMM (R6
//      interleaved read->MFMA serially, exposing ~100cy latency per slice;
//      batched issue lets the compiler emit the fine-grained lgkmcnt(N)
//      pipeline), 4 independent 8-deep MFMA chains behind the queue;
//  (b) __launch_bounds__(256,1): full 512-reg budget/wave, no spill
//      (weights 256 in AGPR/VGPR + batch 32 + misc ~80 < 450).
//
// Swapped trick: S^T = W^T @ z^T (weights as MFMA A-operand). C/D layout:
// col(lane&15) = batch row m, row(q*4+r) = output col c. LDS round-trip is
// per-m contiguous: packed b64 writes, b128 frag reads, row stride 264 u16.
// Rotated k-slice order ks=(2wv+i)&7; weight frags PRE-ROTATED at load so
// all hot-loop register indices are static (R4: runtime idx -> scratch).

#define BS   1024
#define ZDIM 256
#define TLEN 128
#define ROWSTRIDE 264   // u16 units; 528 B = 16B-aligned, odd multiple of 4 units

typedef short v8s __attribute__((ext_vector_type(8)));
typedef float v4f __attribute__((ext_vector_type(4)));

static __device__ __forceinline__ ushort f2bf_rne(float x) {
    union { float f; unsigned u; } v; v.f = x;
    unsigned r = v.u + 0x7FFFu + ((v.u >> 16) & 1u);
    return (ushort)(r >> 16);
}

static __device__ __forceinline__ unsigned pk2(float a, float b) {
    union { __hip_bfloat162 h; unsigned u; } cv;
    cv.h = __float22bfloat162_rn(make_float2(a, b));
    return cv.u;
}

static __device__ __forceinline__ float fast_tanh(float x) {
    // tanh(x) = 1 - 2/(exp2(2x*log2e)+1); v_exp + v_rcp, no slow libm div
    float e = __builtin_amdgcn_exp2f(2.88539008177793f * x);
    float r = __builtin_amdgcn_rcpf(e + 1.0f);
    return 1.0f - 2.0f * r;
}

__global__ __launch_bounds__(256, 1)
void ode_mfma_kernel(const float* __restrict__ z0,
                     const float* __restrict__ t,
                     const float* __restrict__ W1,
                     const float* __restrict__ b1,
                     const float* __restrict__ W2,
                     const float* __restrict__ b2,
                     float* __restrict__ out)
{
    // state buffers, swapped layout: buf[m][c] bf16, row stride ROWSTRIDE
    __shared__ ushort zbuf[16 * ROWSTRIDE];
    __shared__ ushort hbuf[16 * ROWSTRIDE];
    __shared__ float  hsh[TLEN];            // per-step h = t[s+1]-t[s]

    const int tid  = threadIdx.x;
    const int wv   = tid >> 6;        // 0..3
    const int lane = tid & 63;
    const int q    = lane >> 4;       // 0..3
    const int ln   = lane & 15;       // = batch row m (within tile)
    const int rowbase = blockIdx.x * 16;

    if (tid < TLEN - 1) hsh[tid] = t[tid + 1] - t[tid];

    // ---- one-time: weights -> registers, A-frag layout, PRE-ROTATED ----
    // wf[ct][i] holds k-slice ks=(2wv+i)&7:
    //   lane has W[k=32ks+8q+j][c = 64wv + 16ct + ln]
    v8s w1f[4][8], w2f[4][8];
    #pragma unroll
    for (int ct = 0; ct < 4; ++ct) {
        const int c = wv * 64 + ct * 16 + ln;
        #pragma unroll
        for (int i = 0; i < 8; ++i) {
            const int ks = (2 * wv + i) & 7;
            v8s a, b;
            #pragma unroll
            for (int j = 0; j < 8; ++j) {
                const int k = ks * 32 + q * 8 + j;
                a[j] = (short)f2bf_rne(W1[k * ZDIM + c]);
                b[j] = (short)f2bf_rne(W2[k * ZDIM + c]);
            }
            w1f[ct][i] = a;
            w2f[ct][i] = b;
        }
    }

    // biases in C'-layout: value row (c = 64wv + 16ct + 4q + r)
    v4f b1f[4], b2f[4];
    #pragma unroll
    for (int ct = 0; ct < 4; ++ct)
        #pragma unroll
        for (int r = 0; r < 4; ++r) {
            b1f[ct][r] = b1[wv * 64 + ct * 16 + q * 4 + r];
            b2f[ct][r] = b2[wv * 64 + ct * 16 + q * 4 + r];
        }

    // LDS offsets (u16 units); rdaddr[i] carries the matching slice rotation
    const int rdbase = ln * ROWSTRIDE + q * 8;            // + 32*ks, b128 reads
    const int wrbase = ln * ROWSTRIDE + wv * 64 + q * 4;  // + 16*ct,  b64 writes
    int rdaddr[8];
    #pragma unroll
    for (int i = 0; i < 8; ++i)
        rdaddr[i] = rdbase + ((2 * wv + i) & 7) * 32;

    // ---- initial state ----
    float zloc[4][4];   // z[m=ln][c = 64wv+16ct+4q+r], fp32
    #pragma unroll
    for (int ct = 0; ct < 4; ++ct) {
        #pragma unroll
        for (int r = 0; r < 4; ++r)
            zloc[ct][r] = z0[(rowbase + ln) * ZDIM + wv * 64 + ct * 16 + q * 4 + r];
        uint2 p; p.x = pk2(zloc[ct][0], zloc[ct][1]); p.y = pk2(zloc[ct][2], zloc[ct][3]);
        *(uint2*)&zbuf[wrbase + ct * 16] = p;
    }
    __syncthreads();

    float kacc[4][4];

    #pragma unroll 1
    for (int step = 0; step < TLEN - 1; ++step) {
        const float h = hsh[step];

        #pragma unroll
        for (int stage = 0; stage < 4; ++stage) {
            // ---- GEMM1: S^T = W1^T z^T + b1 ----
            // batch-issue ALL 8 b128 reads, then 4 independent 8-deep chains
            {
                v8s zf[8];
                #pragma unroll
                for (int i = 0; i < 8; ++i)
                    zf[i] = *(const v8s*)&zbuf[rdaddr[i]];
                v4f a0 = b1f[0], a1 = b1f[1], a2 = b1f[2], a3 = b1f[3];
                #pragma unroll
                for (int i = 0; i < 8; ++i) {
                    a0 = __builtin_amdgcn_mfma_f32_16x16x32_bf16(w1f[0][i], zf[i], a0, 0, 0, 0);
                    a1 = __builtin_amdgcn_mfma_f32_16x16x32_bf16(w1f[1][i], zf[i], a1, 0, 0, 0);
                    a2 = __builtin_amdgcn_mfma_f32_16x16x32_bf16(w1f[2][i], zf[i], a2, 0, 0, 0);
                    a3 = __builtin_amdgcn_mfma_f32_16x16x32_bf16(w1f[3][i], zf[i], a3, 0, 0, 0);
                }
                // tanh -> hbuf; write each ct as soon as it's packed
                uint2 p;
                p.x = pk2(fast_tanh(a0[0]), fast_tanh(a0[1]));
                p.y = pk2(fast_tanh(a0[2]), fast_tanh(a0[3]));
                *(uint2*)&hbuf[wrbase] = p;
                p.x = pk2(fast_tanh(a1[0]), fast_tanh(a1[1]));
                p.y = pk2(fast_tanh(a1[2]), fast_tanh(a1[3]));
                *(uint2*)&hbuf[wrbase + 16] = p;
                p.x = pk2(fast_tanh(a2[0]), fast_tanh(a2[1]));
                p.y = pk2(fast_tanh(a2[2]), fast_tanh(a2[3]));
                *(uint2*)&hbuf[wrbase + 32] = p;
                p.x = pk2(fast_tanh(a3[0]), fast_tanh(a3[1]));
                p.y = pk2(fast_tanh(a3[2]), fast_tanh(a3[3]));
                *(uint2*)&hbuf[wrbase + 48] = p;
            }
            __syncthreads();

            // ---- GEMM2: f^T = W2^T h^T + b2 (same batched structure) ----
            v4f f0 = b2f[0], f1 = b2f[1], f2 = b2f[2], f3 = b2f[3];
            {
                v8s hf[8];
                #pragma unroll
                for (int i = 0; i < 8; ++i)
                    hf[i] = *(const v8s*)&hbuf[rdaddr[i]];
                #pragma unroll
                for (int i = 0; i < 8; ++i) {
                    f0 = __builtin_amdgcn_mfma_f32_16x16x32_bf16(w2f[0][i], hf[i], f0, 0, 0, 0);
                    f1 = __builtin_amdgcn_mfma_f32_16x16x32_bf16(w2f[1][i], hf[i], f1, 0, 0, 0);
                    f2 = __builtin_amdgcn_mfma_f32_16x16x32_bf16(w2f[2][i], hf[i], f2, 0, 0, 0);
                    f3 = __builtin_amdgcn_mfma_f32_16x16x32_bf16(w2f[3][i], hf[i], f3, 0, 0, 0);
                }
            }
            v4f fa[4] = { f0, f1, f2, f3 };

            // ---- RK4 epilogue: only zn pack+write before the barrier ----
            if (stage < 3) {
                const float c = (stage == 2) ? h : 0.5f * h;
                #pragma unroll
                for (int ct = 0; ct < 4; ++ct) {
                    float zn[4];
                    #pragma unroll
                    for (int r = 0; r < 4; ++r) zn[r] = zloc[ct][r] + c * fa[ct][r];
                    uint2 p; p.x = pk2(zn[0], zn[1]); p.y = pk2(zn[2], zn[3]);
                    *(uint2*)&zbuf[wrbase + ct * 16] = p;
                }
                __syncthreads();
                // deferred kacc bookkeeping: overlaps next GEMM1's reads
                #pragma unroll
                for (int ct = 0; ct < 4; ++ct)
                    #pragma unroll
                    for (int r = 0; r < 4; ++r) {
                        if (stage == 0) kacc[ct][r] = fa[ct][r];
                        else            kacc[ct][r] += 2.0f * fa[ct][r];
                    }
            } else {
                #pragma unroll
                for (int ct = 0; ct < 4; ++ct) {
                    #pragma unroll
                    for (int r = 0; r < 4; ++r) {
                        kacc[ct][r] += fa[ct][r];
                        zloc[ct][r] += (h * (1.0f / 6.0f)) * kacc[ct][r];
                    }
                    uint2 p; p.x = pk2(zloc[ct][0], zloc[ct][1]);
                    p.y = pk2(zloc[ct][2], zloc[ct][3]);
                    *(uint2*)&zbuf[wrbase + ct * 16] = p;
                }
                __syncthreads();
            }
        }
    }

    // ---- final store (one-time, uncoalesced is fine) ----
    #pragma unroll
    for (int ct = 0; ct < 4; ++ct)
        #pragma unroll
        for (int r = 0; r < 4; ++r)
            out[(rowbase + ln) * ZDIM + wv * 64 + ct * 16 + q * 4 + r] = zloc[ct][r];
}

extern "C" void kernel_launch(void* const* d_in, const int* in_sizes, int n_in,
                              void* d_out, int out_size, void* d_ws, size_t ws_size,
                              hipStream_t stream) {
    const float* z0 = (const float*)d_in[0];
    const float* t  = (const float*)d_in[1];
    const float* W1 = (const float*)d_in[2];
    const float* b1 = (const float*)d_in[3];
    const float* W2 = (const float*)d_in[4];
    const float* b2 = (const float*)d_in[5];
    float* out = (float*)d_out;

    dim3 grid(BS / 16);    // 64 workgroups, 16 batch rows each
    dim3 block(256);       // 4 waves, 1 per SIMD, 64 cols each
    hipLaunchKernelGGL(ode_mfma_kernel, grid, block, 0, stream,
                       z0, t, W1, b1, W2, b2, out);
}